// Round 14
// baseline (293.857 us; speedup 1.0000x reference)
//
#include <hip/hip_runtime.h>
#include <math.h>

constexpr int KK = 2;
constexpr int HH = 4;
constexpr int NN = 4096;
constexpr int DD = 64;
constexpr int OO = 64;
constexpr int NU = 4000;
constexpr int CC = 2;
constexpr int JSPLIT = 2;
constexpr int JCHUNK = NN / JSPLIT;  // 2048
constexpr float LOG2E = 1.44269504088896340736f;

typedef float vf4 __attribute__((ext_vector_type(4)));
typedef float vf2 __attribute__((ext_vector_type(2)));

__device__ __forceinline__ float fexp2(float x) {
#if __has_builtin(__builtin_amdgcn_exp2f)
  return __builtin_amdgcn_exp2f(x);
#else
  return exp2f(x);
#endif
}
__device__ __forceinline__ float frcp(float x) {
#if __has_builtin(__builtin_amdgcn_rcpf)
  return __builtin_amdgcn_rcpf(x);
#else
  return 1.0f / x;
#endif
}
__device__ __forceinline__ float ftanh(float x) {
  float e = fexp2(x * (2.0f * LOG2E));
  return 1.0f - 2.0f * frcp(e + 1.0f);
}

// ---------------------------------------------------------------------------
// Phase 1: per (k,h): hp = h @ w; per node (SoA planes, factorized):
//   srcAA[kh][i] = {2^src', 2^(0.2 src')}
//   Bp[kh][j]=2^dst', B5p[kh][j]=2^(0.2 dst'), g0p/g1p[kh][j]=hp_j.fc_w_c
// exp2(leaky(s)) == max(A*B, A5*B5)  (exact identity, validated R9-R13).
// 16-ROW blocks: grid (256, K*H), block 256, thread = 1 row x 4 o.
// LDS 26 KB -> 6 blocks/CU; 2048 blocks; 4x shorter chains than 64-row.
// ---------------------------------------------------------------------------
__global__ __launch_bounds__(256) void gat_phase1(
    const float* __restrict__ hsrc, const float* __restrict__ w,
    const float* __restrict__ a_src, const float* __restrict__ a_dst,
    const float* __restrict__ fc_w,
    float* __restrict__ srcAA, float* __restrict__ Bp,
    float* __restrict__ B5p, float* __restrict__ g0p,
    float* __restrict__ g1p) {
  const int kh = blockIdx.y;  // 0..7
  const int k = kh >> 2;
  const int i0 = blockIdx.x * 16;
  const int tid = threadIdx.x;

  __shared__ float w_s[DD][OO];      // 16 KB
  __shared__ float h_s[DD][20];      // 5 KB (16 rows + pad)
  __shared__ float part[4][16][17];  // 4.3 KB

  {
    const vf4* wp = (const vf4*)(w + (size_t)kh * DD * OO);
    vf4* ws4 = (vf4*)w_s;
#pragma unroll
    for (int t = tid; t < DD * OO / 4; t += 256) ws4[t] = wp[t];
  }
  {  // stage h transposed: 16 rows x 16 vf4, one per thread
    const int row = tid >> 4;
    const int f4 = (tid & 15) * 4;
    vf4 v = *(const vf4*)(hsrc + (size_t)(i0 + row) * DD + f4);
    h_s[f4 + 0][row] = v.x;
    h_s[f4 + 1][row] = v.y;
    h_s[f4 + 2][row] = v.z;
    h_s[f4 + 3][row] = v.w;
  }
  __syncthreads();

  const int og = tid & 15;  // o0 = og*4
  const int r = tid >> 4;   // row 0..15
  const int o0 = og * 4;

  vf4 hp = (vf4)(0.0f);
#pragma unroll 16
  for (int f = 0; f < DD; ++f) {
    float hv = h_s[f][r];
    vf4 wv = *(const vf4*)&w_s[f][o0];
    hp.x = fmaf(hv, wv.x, hp.x);
    hp.y = fmaf(hv, wv.y, hp.y);
    hp.z = fmaf(hv, wv.z, hp.z);
    hp.w = fmaf(hv, wv.w, hp.w);
  }

  {
    float sp = 0.0f, dp = 0.0f, g0 = 0.0f, g1 = 0.0f;
#pragma unroll
    for (int u = 0; u < 4; ++u) {
      float v = (u == 0) ? hp.x : (u == 1) ? hp.y : (u == 2) ? hp.z : hp.w;
      float t = ftanh(v);
      sp = fmaf(t, a_src[kh * OO + o0 + u], sp);
      dp = fmaf(t, a_dst[kh * OO + o0 + u], dp);
      g0 = fmaf(v, fc_w[0 * (KK * OO) + k * OO + o0 + u], g0);
      g1 = fmaf(v, fc_w[1 * (KK * OO) + k * OO + o0 + u], g1);
    }
    part[0][r][og] = sp;
    part[1][r][og] = dp;
    part[2][r][og] = g0;
    part[3][r][og] = g1;
  }
  __syncthreads();

  if (tid < 64) {  // thread = (row, val): sum 16 og-partials, write out
    const int val = tid & 3;
    const int row = tid >> 2;
    const float* pr = &part[val][row][0];
    vf4 s0 = *(const vf4*)(pr + 0);
    vf4 s1 = *(const vf4*)(pr + 4);
    vf4 s2 = *(const vf4*)(pr + 8);
    vf4 s3 = *(const vf4*)(pr + 12);
    vf4 t4 = s0 + s1 + s2 + s3;
    float sum = t4.x + t4.y + t4.z + t4.w;
    const size_t idx = (size_t)kh * NN + i0 + row;
    if (val == 0) {
      float sp = sum * LOG2E;
      vf2 v = {fexp2(sp), fexp2(0.2f * sp)};
      *(vf2*)(srcAA + idx * 2) = v;
    } else if (val == 1) {
      float dp = sum * LOG2E;
      Bp[idx] = fexp2(dp);
      B5p[idx] = fexp2(0.2f * dp);
    } else if (val == 2) {
      g0p[idx] = sum;
    } else {
      g1p[idx] = sum;
    }
  }
}

// ---------------------------------------------------------------------------
// Phase 2: grid (NU/2, K*JSPLIT), block = 64 = ONE wave, <=64 VGPR by
// construction (launch_bounds(64,8) -> 8 waves/SIMD resident, TLP covers
// all latency; no prefetch registers, no LDS in the hot loop).
// Wave = 2 rows x 2048-j chunk (8 tiles of 256 j), lane = j-quad; every
// load (adj, B, B5, g0, g1) is dense vf4. A-factors wave-uniform (SGPR).
//   e = max(A*B, A5*B5); pa = e*adj; l += pa; a_c += pa*g_c
// Live set: 24 acc + 8 adj + 16 plane + addr ~= 60 VGPR.
// Butterfly(24) -> lane0 writes partials P[k][chunk][h][{l,a0,a1}][i].
// ---------------------------------------------------------------------------
__global__ __launch_bounds__(64, 8) void gat_phase2(
    const float* __restrict__ adj, const float* __restrict__ srcAA,
    const float* __restrict__ Bp, const float* __restrict__ B5p,
    const float* __restrict__ g0p, const float* __restrict__ g1p,
    float* __restrict__ P) {
  const int k = blockIdx.y >> 1;
  const int chunk = blockIdx.y & 1;
  const int r0 = blockIdx.x * 2;
  const int lane = threadIdx.x;

  // wave-uniform A factors -> SGPRs
  float A[2][4], A5[2][4];
#pragma unroll
  for (int h = 0; h < 4; ++h) {
    const float* base = srcAA + ((size_t)(k * HH + h) * NN + r0) * 2;
#pragma unroll
    for (int r = 0; r < 2; ++r) {
      A[r][h] = base[r * 2 + 0];
      A5[r][h] = base[r * 2 + 1];
    }
  }

  float l[2][4], a0[2][4], a1[2][4];
#pragma unroll
  for (int r = 0; r < 2; ++r)
#pragma unroll
    for (int h = 0; h < 4; ++h) {
      l[r][h] = 0.0f;
      a0[r][h] = 0.0f;
      a1[r][h] = 0.0f;
    }

  const float* adjr0 =
      adj + (size_t)k * NN * NN + (size_t)r0 * NN + chunk * JCHUNK + lane * 4;
  const float* adjr1 = adjr0 + NN;
  const size_t pbase = chunk * JCHUNK + lane * 4;

#pragma unroll 1
  for (int t = 0; t < 8; ++t) {
    vf4 av0 = *(const vf4*)(adjr0 + t * 256);
    vf4 av1 = *(const vf4*)(adjr1 + t * 256);
#pragma unroll
    for (int h = 0; h < 4; ++h) {
      const size_t pb = (size_t)(k * HH + h) * NN + pbase + t * 256;
      vf4 b = *(const vf4*)(Bp + pb);
      vf4 b5 = *(const vf4*)(B5p + pb);
      vf4 g0 = *(const vf4*)(g0p + pb);
      vf4 g1 = *(const vf4*)(g1p + pb);
      vf2 blo = {b.x, b.y}, bhi = {b.z, b.w};
      vf2 b5lo = {b5.x, b5.y}, b5hi = {b5.z, b5.w};
#pragma unroll
      for (int r = 0; r < 2; ++r) {
        vf2 elo = __builtin_elementwise_max(blo * A[r][h], b5lo * A5[r][h]);
        vf2 ehi = __builtin_elementwise_max(bhi * A[r][h], b5hi * A5[r][h]);
        vf4 av = (r == 0) ? av0 : av1;
        float p0 = elo.x * av.x;
        float p1 = elo.y * av.y;
        float p2 = ehi.x * av.z;
        float p3 = ehi.y * av.w;
        l[r][h] += (p0 + p1) + (p2 + p3);
        a0[r][h] = fmaf(p0, g0.x,
                        fmaf(p1, g0.y, fmaf(p2, g0.z, fmaf(p3, g0.w, a0[r][h]))));
        a1[r][h] = fmaf(p0, g1.x,
                        fmaf(p1, g1.y, fmaf(p2, g1.z, fmaf(p3, g1.w, a1[r][h]))));
      }
    }
  }

  // butterfly across 64 lanes (24 scalars)
#pragma unroll
  for (int r = 0; r < 2; ++r)
#pragma unroll
    for (int h = 0; h < 4; ++h) {
      float x0 = l[r][h], x1 = a0[r][h], x2 = a1[r][h];
#pragma unroll
      for (int off = 32; off > 0; off >>= 1) {
        x0 += __shfl_xor(x0, off, 64);
        x1 += __shfl_xor(x1, off, 64);
        x2 += __shfl_xor(x2, off, 64);
      }
      l[r][h] = x0;
      a0[r][h] = x1;
      a1[r][h] = x2;
    }

  if (lane == 0) {
#pragma unroll
    for (int r = 0; r < 2; ++r)
#pragma unroll
      for (int h = 0; h < 4; ++h) {
        // P layout: [k][chunk][h][{l,a0,a1}][i]
        size_t base =
            (((size_t)(k * JSPLIT + chunk) * HH + h) * 3) * NU + (r0 + r);
        P[base] = l[r][h];
        P[base + NU] = a0[r][h];
        P[base + 2 * (size_t)NU] = a1[r][h];
      }
  }
}

// ---------------------------------------------------------------------------
// Phase 3: combine chunk partials, divide, mean heads, sum kinds, +bias,
// log_softmax over C=2.
// ---------------------------------------------------------------------------
__global__ __launch_bounds__(256) void gat_phase3(
    const float* __restrict__ P, const float* __restrict__ fc_b,
    float* __restrict__ out) {
  const int i = blockIdx.x * 256 + threadIdx.x;
  if (i >= NU) return;
  float l0 = fc_b[0], l1 = fc_b[1];
#pragma unroll
  for (int k = 0; k < KK; ++k) {
#pragma unroll
    for (int q = 0; q < HH; ++q) {
      float ls = 0.0f, a0 = 0.0f, a1 = 0.0f;
#pragma unroll
      for (int ch = 0; ch < JSPLIT; ++ch) {
        size_t b = (((size_t)(k * JSPLIT + ch) * HH + q) * 3) * NU + i;
        ls += P[b];
        a0 += P[b + NU];
        a1 += P[b + 2 * (size_t)NU];
      }
      float inv = 1.0f / ls;
      l0 = fmaf(0.25f * a0, inv, l0);
      l1 = fmaf(0.25f * a1, inv, l1);
    }
  }
  float m = fmaxf(l0, l1);
  float lse = m + logf(expf(l0 - m) + expf(l1 - m));
  out[i * CC + 0] = l0 - lse;
  out[i * CC + 1] = l1 - lse;
}

extern "C" void kernel_launch(void* const* d_in, const int* in_sizes, int n_in,
                              void* d_out, int out_size, void* d_ws, size_t ws_size,
                              hipStream_t stream) {
  const float* hsrc  = (const float*)d_in[0];  // (1,4096,64)
  const float* hadj  = (const float*)d_in[1];  // (2,1,4096,4096)
  const float* w     = (const float*)d_in[2];  // (2,4,64,64)
  const float* a_src = (const float*)d_in[3];  // (2,4,64,1)
  const float* a_dst = (const float*)d_in[4];  // (2,4,64,1)
  const float* fc_w  = (const float*)d_in[5];  // (2,128)
  const float* fc_b  = (const float*)d_in[6];  // (2,)
  float* out = (float*)d_out;                  // (1,4000,2) fp32

  char* ws = (char*)d_ws;
  float* srcAA = (float*)(ws + 0);        // K*H*N*2 (256 KB)
  float* Bp    = (float*)(ws + 262144);   // K*H*N (128 KB each)
  float* B5p   = (float*)(ws + 393216);
  float* g0p   = (float*)(ws + 524288);
  float* g1p   = (float*)(ws + 655360);
  float* P     = (float*)(ws + 786432);   // K*JSPLIT*H*3*NU (~768 KB)

  dim3 g1(NN / 16, KK * HH);
  gat_phase1<<<g1, 256, 0, stream>>>(hsrc, w, a_src, a_dst, fc_w,
                                     srcAA, Bp, B5p, g0p, g1p);
  dim3 g2(NU / 2, KK * JSPLIT);
  gat_phase2<<<g2, 64, 0, stream>>>(hadj, srcAA, Bp, B5p, g0p, g1p, P);
  gat_phase3<<<(NU + 255) / 256, 256, 0, stream>>>(P, fc_b, out);
}